// Round 10
// baseline (250.328 us; speedup 1.0000x reference)
//
#include <hip/hip_runtime.h>

// SignSemanticsAggregator on MI355X (gfx950), round 10.
// E = sp + 32*sn (i8); E@E digits: M_same=(acc&31)+(acc>>10), M_diff=(acc>>5)&31.
// Round-10: NO LDS, NO barriers in the GEMM — MFMA fragments are loaded
// directly global->VGPR from L2/L3-resident E/ET with a register
// double-buffered K-loop (manual unroll-2, compiler-counted vmcnt).
// 528 upper-tri 128x128 blocks, 4 free-running waves of 64x64 each.

#define NN 4096
#define NW 128
#define MASK_BYTES ((size_t)NN * NW * 4)     // 2 MiB per mask
#define MASK_WORDS ((size_t)NN * NW)

typedef unsigned int u32;
typedef __attribute__((ext_vector_type(4))) int int4v;
typedef __attribute__((ext_vector_type(4))) float f32x4;

// ---------------- preprocessing ----------------

__global__ void scatter_all(const int* __restrict__ e0, const int* __restrict__ e1,
                            const int* __restrict__ e2, const int* __restrict__ e3,
                            int E0, int E1, int E2, int E3,
                            u32* __restrict__ ws) {
    int i = blockIdx.x * blockDim.x + threadIdx.x;
    u32* Pt = ws + 0 * MASK_WORDS;
    u32* P1 = ws + 1 * MASK_WORDS;
    u32* Nt = ws + 2 * MASK_WORDS;
    u32* N1 = ws + 3 * MASK_WORDS;
    if (i < E0) { int r = e0[i], c = e0[i + E0];
        atomicOr(&Pt[r * NW + (c >> 5)], 1u << (c & 31)); }
    if (i < E1) { int r = e1[i], c = e1[i + E1];
        atomicOr(&P1[r * NW + (c >> 5)], 1u << (c & 31)); }
    if (i < E2) { int r = e2[i], c = e2[i + E2];
        atomicOr(&Nt[r * NW + (c >> 5)], 1u << (c & 31)); }
    if (i < E3) { int r = e3[i], c = e3[i + E3];
        atomicOr(&N1[r * NW + (c >> 5)], 1u << (c & 31)); }
}

// Expand 16 mask bits (sp, sn) -> 16 i8 of E = sp + 32*sn.
__device__ __forceinline__ int4v expand_e(u32 sp, u32 sn) {
    int4v E;
    #pragma unroll
    for (int i = 0; i < 4; i++) {
        u32 p = (((sp >> (4 * i)) & 0xFu) * 0x00204081u) & 0x01010101u;
        u32 n = (((sn >> (4 * i)) & 0xFu) * 0x00204081u) & 0x01010101u;
        E[i] = (int)(p | (n << 5));
    }
    return E;
}

// Blocks [0,2048): E row-wise from P1/N1. Blocks [2048,4096): ET via in-wave
// ballot bit-transpose. Pos-priority and diagonal clearing in both halves.
__global__ void build_both(const u32* __restrict__ masks,
                           char* __restrict__ E, char* __restrict__ ET) {
    const u32* P  = masks + 1 * MASK_WORDS;
    const u32* Nm = masks + 3 * MASK_WORDS;
    if (blockIdx.x < 2048) {
        int w = blockIdx.x * 256 + threadIdx.x;      // word index a*128 + col
        u32 p = P[w];
        u32 n = Nm[w] & ~p;
        int a = w >> 7, col = w & 127;
        if ((a >> 5) == col) {
            u32 db = 1u << (a & 31);
            p &= ~db; n &= ~db;
        }
        char* dst = E + (size_t)a * NN + col * 32;
        *reinterpret_cast<int4v*>(dst)      = expand_e(p & 0xFFFFu, n & 0xFFFFu);
        *reinterpret_cast<int4v*>(dst + 16) = expand_e(p >> 16, n >> 16);
    } else {
        int gw = (blockIdx.x - 2048) * 4 + (threadIdx.x >> 6);  // 8192 waves
        int lane = threadIdx.x & 63;
        int ab = gw >> 7;        // 64-row block of a
        int wc = gw & 127;       // word column (c-block of 32)
        u32 pw = P[(ab * 64 + lane) * NW + wc];
        u32 nw = Nm[(ab * 64 + lane) * NW + wc];
        u32 myp = 0, myn = 0;
        #pragma unroll
        for (int j = 0; j < 32; j++) {
            unsigned long long bp = __ballot((pw >> j) & 1u);
            unsigned long long bn = __ballot((nw >> j) & 1u);
            if ((lane & 31) == j) {
                myp = (lane < 32) ? (u32)bp : (u32)(bp >> 32);
                myn = (lane < 32) ? (u32)bn : (u32)(bn >> 32);
            }
        }
        u32 p = myp;
        u32 n = myn & ~p;
        int c = wc * 32 + (lane & 31);
        int abase = ab * 64 + (lane >> 5) * 32;
        if (c >= abase && c < abase + 32) {          // clear diagonal a == c
            u32 db = 1u << (c - abase);
            p &= ~db; n &= ~db;
        }
        char* dst = ET + (size_t)c * NN + abase;
        *reinterpret_cast<int4v*>(dst)      = expand_e(p & 0xFFFFu, n & 0xFFFFu);
        *reinterpret_cast<int4v*>(dst + 16) = expand_e(p >> 16, n >> 16);
    }
}

// ---------------- fused GEMM + epilogue (no LDS, no barriers) ----------------
__global__ __launch_bounds__(256, 2) void gemm_ep(
    const char* __restrict__ E, const char* __restrict__ ET,
    const u32* __restrict__ Pt, const u32* __restrict__ P1,
    const u32* __restrict__ Nt, const u32* __restrict__ N1,
    float* __restrict__ out)
{
    const int tid = threadIdx.x;
    const size_t plane = (size_t)NN * NN;

    // triangular tile map with bijective XCD swizzle (528 = 8 * 66)
    int s_ = ((int)blockIdx.x & 7) * 66 + ((int)blockIdx.x >> 3);
    int by = (int)((65.0f - sqrtf(4225.0f - 8.0f * (float)s_)) * 0.5f);
    if (by > 31) by = 31;
    while (by > 0 && 32 * by - (by * (by - 1)) / 2 > s_) --by;
    while (32 * (by + 1) - ((by + 1) * by) / 2 <= s_) ++by;
    int bx = by + s_ - (32 * by - (by * (by - 1)) / 2);
    const int a0 = by << 7, c0 = bx << 7;

    const int wave = tid >> 6, lane = tid & 63;
    const int wr = (wave >> 1) * 64, wcol = (wave & 1) * 64;
    const int lr = lane & 15, lg = lane >> 4;

    // per-m / per-n fragment base pointers (lane-resolved, K-contiguous)
    const char* pa0 = E  + (size_t)(a0 + wr + lr) * NN + lg * 16;
    const char* pb0 = ET + (size_t)(c0 + wcol + lr) * NN + lg * 16;
    const char* pa1 = pa0 + 16 * NN;
    const char* pa2 = pa0 + 32 * NN;
    const char* pa3 = pa0 + 48 * NN;
    const char* pb1 = pb0 + 16 * NN;
    const char* pb2 = pb0 + 32 * NN;
    const char* pb3 = pb0 + 48 * NN;

    int4v acc[4][4];
    int4v zero = {0, 0, 0, 0};
    #pragma unroll
    for (int m = 0; m < 4; m++)
        #pragma unroll
        for (int n = 0; n < 4; n++) acc[m][n] = zero;

    int4v aX[4], bX[4], aY[4], bY[4];

    #define LOADSET(A, B, koff)                                          \
        do {                                                             \
            A[0] = *reinterpret_cast<const int4v*>(pa0 + (koff));        \
            A[1] = *reinterpret_cast<const int4v*>(pa1 + (koff));        \
            A[2] = *reinterpret_cast<const int4v*>(pa2 + (koff));        \
            A[3] = *reinterpret_cast<const int4v*>(pa3 + (koff));        \
            B[0] = *reinterpret_cast<const int4v*>(pb0 + (koff));        \
            B[1] = *reinterpret_cast<const int4v*>(pb1 + (koff));        \
            B[2] = *reinterpret_cast<const int4v*>(pb2 + (koff));        \
            B[3] = *reinterpret_cast<const int4v*>(pb3 + (koff));        \
        } while (0)

    #define MFMAS(A, B)                                                  \
        do {                                                             \
            __builtin_amdgcn_s_setprio(1);                               \
            _Pragma("unroll")                                            \
            for (int m = 0; m < 4; m++)                                  \
                _Pragma("unroll")                                        \
                for (int n = 0; n < 4; n++)                              \
                    acc[m][n] = __builtin_amdgcn_mfma_i32_16x16x64_i8(   \
                        A[m], B[n], acc[m][n], 0, 0, 0);                 \
            __builtin_amdgcn_s_setprio(0);                               \
        } while (0)

    LOADSET(aX, bX, 0);                       // t = 0
    for (int t = 0; t < 64; t += 2) {
        if (t + 1 < 64) LOADSET(aY, bY, (t + 1) * 64);
        MFMAS(aX, bX);                        // waits only on aX/bX (counted)
        if (t + 2 < 64) LOADSET(aX, bX, (t + 2) * 64);
        MFMAS(aY, bY);
    }
    #undef LOADSET
    #undef MFMAS

    // ---- fused epilogue: C/D layout col=lane&15, row=(lane>>4)*4+q ----
    #pragma unroll
    for (int m = 0; m < 4; m++) {
        #pragma unroll
        for (int n = 0; n < 4; n++) {
            #pragma unroll
            for (int q = 0; q < 4; q++) {
                int a = a0 + wr + m * 16 + lg * 4 + q;
                int c = c0 + wcol + n * 16 + lr;
                int widx = a * NW + (c >> 5);
                int bit = c & 31;
                u32 p1 = (P1[widx] >> bit) & 1u;
                u32 n1 = (N1[widx] >> bit) & 1u;
                u32 pt = (Pt[widx] >> bit) & 1u;
                u32 nt = (Nt[widx] >> bit) & 1u;
                int av = acc[m][n][q];
                int Ms = (av & 31) + (av >> 10);     // d0 + d2
                int Md = (av >> 5) & 31;             // d1
                int o0 = (int)(pt ^ p1) + ((a < c && !p1) ? Ms : 0);
                int o1 = (int)(nt ^ n1) + ((a < c && !n1) ? Md : 0);
                size_t oi = (size_t)a * NN + c;
                out[oi] = (float)o0;
                out[plane + oi] = (float)o1;
            }
        }
    }

    // ---- mirror tile xor (strictly-lower mirror), fire-and-forget ----
    if (by != bx) {
        #pragma unroll 4
        for (int pass = 0; pass < 16; ++pass) {
            int e = pass * 1024 + tid * 4;       // element in 128x128 tile
            int r = e >> 7, cc = e & 127;
            int widx = (c0 + r) * NW + ((a0 + cc) >> 5);
            int sh = cc & 31;
            u32 xp = (P1[widx] ^ Pt[widx]) >> sh;
            u32 xn = (N1[widx] ^ Nt[widx]) >> sh;
            f32x4 o0, o1;
            #pragma unroll
            for (int i = 0; i < 4; i++) {
                o0[i] = (float)((xp >> i) & 1u);
                o1[i] = (float)((xn >> i) & 1u);
            }
            size_t ob = (size_t)(c0 + r) * NN + a0 + cc;
            *reinterpret_cast<f32x4*>(out + ob) = o0;
            *reinterpret_cast<f32x4*>(out + plane + ob) = o1;
        }
    }
}

extern "C" void kernel_launch(void* const* d_in, const int* in_sizes, int n_in,
                              void* d_out, int out_size, void* d_ws, size_t ws_size,
                              hipStream_t stream) {
    char* ws = (char*)d_ws;
    u32* masks = (u32*)ws;                    // Pt,P1,Nt,N1 (4 x 2 MiB)
    u32* Pt = masks + 0 * MASK_WORDS;
    u32* P1 = masks + 1 * MASK_WORDS;
    u32* Nt = masks + 2 * MASK_WORDS;
    u32* N1 = masks + 3 * MASK_WORDS;
    char* E  = ws + 4 * MASK_BYTES;           // 16 MiB, linear
    char* ET = E + (size_t)NN * NN;           // 16 MiB, linear
    // ws use: 8 MiB masks + 32 MiB E/ET = 40 MiB

    hipMemsetAsync(d_ws, 0, 4 * MASK_BYTES, stream);

    // input order: A_pos_t, A_pos_tp1, A_neg_t, A_neg_tp1
    int E0 = in_sizes[0] / 2, E1 = in_sizes[1] / 2;
    int E2 = in_sizes[2] / 2, E3 = in_sizes[3] / 2;
    int Emax = max(max(E0, E1), max(E2, E3));
    scatter_all<<<(Emax + 255) / 256, 256, 0, stream>>>(
        (const int*)d_in[0], (const int*)d_in[1], (const int*)d_in[2],
        (const int*)d_in[3], E0, E1, E2, E3, masks);

    build_both<<<4096, 256, 0, stream>>>(masks, E, ET);

    gemm_ep<<<528, 256, 0, stream>>>(E, ET, Pt, P1, Nt, N1, (float*)d_out);
}